// Round 4
// baseline (405.882 us; speedup 1.0000x reference)
//
#include <hip/hip_runtime.h>
#include <math.h>

#define HW 409600
#define BB 16
#define CPRED 6
#define NKER 5
#define NBINS 1024
#define CHUNKS 100
#define EPSF 1e-6f

__device__ __forceinline__ float sigmoidf_(float x) {
    return __builtin_amdgcn_rcpf(1.0f + __expf(-x));
}

struct Pix {
    float4 m, g, x;
    float4 xk0, xk1, xk2, xk3, xk4;
    float4 gg0, gg1, gg2, gg3, gg4;
};

__global__ __launch_bounds__(256, 3) void pass1_kernel(
    const float* __restrict__ pred, const float* __restrict__ gt_text,
    const float* __restrict__ gt_k, const float* __restrict__ tmask,
    float* __restrict__ hist_cnt, float* __restrict__ hist_p2,
    float* __restrict__ bstats, float* __restrict__ kstats)
{
    __shared__ float s_cnt[NBINS];
    __shared__ float s_p2[NBINS];
    __shared__ float s_red[19][4];

    const int b = blockIdx.y;
    const int chunk = blockIdx.x;
    const int tid = threadIdx.x;

    for (int i = tid; i < NBINS; i += 256) { s_cnt[i] = 0.f; s_p2[i] = 0.f; }
    __syncthreads();

    const int NV4 = HW / 4;   // 102400 float4 per (b, channel)
    const float4* tm4 = reinterpret_cast<const float4*>(tmask + (size_t)b * HW);
    const float4* gt4 = reinterpret_cast<const float4*>(gt_text + (size_t)b * HW);
    const float4* pt4 = reinterpret_cast<const float4*>(pred + (size_t)b * CPRED * HW);
    const float4* gk4 = reinterpret_cast<const float4*>(gt_k + (size_t)b * NKER * HW);

    const int per = NV4 / CHUNKS;        // 1024 -> exactly 4 iters per thread
    const int base = chunk * per + tid;

    float n_pos = 0.f, n_neg = 0.f, sp = 0.f, sp2 = 0.f;
    float kin0 = 0.f, kin1 = 0.f, kin2 = 0.f, kin3 = 0.f, kin4 = 0.f;
    float kui0 = 0.f, kui1 = 0.f, kui2 = 0.f, kui3 = 0.f, kui4 = 0.f;
    float kut0 = 0.f, kut1 = 0.f, kut2 = 0.f, kut3 = 0.f, kut4 = 0.f;

    #define LOADP(P, idx) { \
        int i_ = (idx); \
        P.m   = tm4[i_]; \
        P.g   = gt4[i_]; \
        P.x   = pt4[i_]; \
        P.xk0 = pt4[(size_t)1 * NV4 + i_]; \
        P.gg0 = gk4[(size_t)0 * NV4 + i_]; \
        P.xk1 = pt4[(size_t)2 * NV4 + i_]; \
        P.gg1 = gk4[(size_t)1 * NV4 + i_]; \
        P.xk2 = pt4[(size_t)3 * NV4 + i_]; \
        P.gg2 = gk4[(size_t)2 * NV4 + i_]; \
        P.xk3 = pt4[(size_t)4 * NV4 + i_]; \
        P.gg3 = gk4[(size_t)3 * NV4 + i_]; \
        P.xk4 = pt4[(size_t)5 * NV4 + i_]; \
        P.gg4 = gk4[(size_t)4 * NV4 + i_]; \
    }

    #define TEXT1(mm, xx, ggt) { \
        float p = sigmoidf_(xx); \
        float posf = (mm) * (ggt); \
        float negf = (mm) - posf; \
        n_pos += posf; n_neg += negf; \
        sp += posf * p; sp2 += posf * p * p; \
        if (negf > 0.f) { \
            int bin = (int)(p * (float)NBINS); \
            bin = bin > NBINS - 1 ? NBINS - 1 : bin; \
            atomicAdd(&s_cnt[bin], 1.f); \
            atomicAdd(&s_p2[bin], p * p); \
        } \
    }

    #define KCH(P, kin, kui, kut, xkf, ggf) { \
        float p0 = sigmoidf_(P.xkf.x), p1 = sigmoidf_(P.xkf.y); \
        float p2_ = sigmoidf_(P.xkf.z), p3 = sigmoidf_(P.xkf.w); \
        kin += P.m.x * p0 * P.ggf.x + P.m.y * p1 * P.ggf.y \
             + P.m.z * p2_ * P.ggf.z + P.m.w * p3 * P.ggf.w; \
        kui += P.m.x * p0 * p0 + P.m.y * p1 * p1 \
             + P.m.z * p2_ * p2_ + P.m.w * p3 * p3; \
        kut += P.m.x * P.ggf.x + P.m.y * P.ggf.y \
             + P.m.z * P.ggf.z + P.m.w * P.ggf.w; \
    }

    #define PROC(P) { \
        TEXT1(P.m.x, P.x.x, P.g.x) \
        TEXT1(P.m.y, P.x.y, P.g.y) \
        TEXT1(P.m.z, P.x.z, P.g.z) \
        TEXT1(P.m.w, P.x.w, P.g.w) \
        KCH(P, kin0, kui0, kut0, xk0, gg0) \
        KCH(P, kin1, kui1, kut1, xk1, gg1) \
        KCH(P, kin2, kui2, kut2, xk2, gg2) \
        KCH(P, kin3, kui3, kut3, xk3, gg3) \
        KCH(P, kin4, kui4, kut4, xk4, gg4) \
    }

    Pix A, B;
    LOADP(A, base)
    #pragma unroll
    for (int k = 0; k < 4; ++k) {
        if (k < 3) LOADP(B, base + (k + 1) * 256)
        PROC(A)
        if (k < 3) A = B;
    }
    #undef LOADP
    #undef TEXT1
    #undef KCH
    #undef PROC

    // wave-level reduction -> LDS -> one global atomic per quantity per block
    const int lane = tid & 63;
    const int wv = tid >> 6;
    float kin[NKER] = {kin0, kin1, kin2, kin3, kin4};
    float kui[NKER] = {kui0, kui1, kui2, kui3, kui4};
    float kut[NKER] = {kut0, kut1, kut2, kut3, kut4};
    #define WRED(v) { for (int o_ = 32; o_ > 0; o_ >>= 1) v += __shfl_down(v, o_, 64); }
    WRED(n_pos) WRED(n_neg) WRED(sp) WRED(sp2)
    if (lane == 0) {
        s_red[0][wv] = n_pos; s_red[1][wv] = n_neg;
        s_red[2][wv] = sp;    s_red[3][wv] = sp2;
    }
    #pragma unroll
    for (int c = 0; c < NKER; ++c) {
        float a = kin[c], u = kui[c], t = kut[c];
        WRED(a) WRED(u) WRED(t)
        if (lane == 0) {
            s_red[4 + c * 3 + 0][wv] = a;
            s_red[4 + c * 3 + 1][wv] = u;
            s_red[4 + c * 3 + 2][wv] = t;
        }
    }
    #undef WRED
    __syncthreads();

    if (tid < 19) {
        float a = s_red[tid][0] + s_red[tid][1] + s_red[tid][2] + s_red[tid][3];
        float* dst;
        if (tid < 4) dst = &bstats[b * 4 + tid];
        else {
            int q = tid - 4;
            dst = &kstats[(b * NKER + q / 3) * 3 + (q % 3)];
        }
        atomicAdd(dst, a);
    }

    for (int i = tid; i < NBINS; i += 256) {
        float c = s_cnt[i];
        if (c != 0.f) {
            atomicAdd(&hist_cnt[b * NBINS + i], c);
            atomicAdd(&hist_p2[b * NBINS + i], s_p2[i]);
        }
    }
}

// one block (1 wave) per batch
__global__ __launch_bounds__(64) void finalize_batch_kernel(
    const float* __restrict__ hist_cnt, const float* __restrict__ hist_p2,
    const float* __restrict__ bstats, const float* __restrict__ kstats,
    float* __restrict__ btext, float* __restrict__ bkterm)
{
    const int b = blockIdx.x;
    const int lane = threadIdx.x;
    const int SEG = NBINS / 64;   // 16 bins per lane

    float cg = 0.f, pg = 0.f;
    {
        int base = b * NBINS + lane * SEG;
        #pragma unroll
        for (int k = 0; k < SEG; ++k) {
            cg += hist_cnt[base + k];
            pg += hist_p2[base + k];
        }
    }
    float pc = cg, pp = pg;
    #pragma unroll
    for (int o = 1; o < 64; o <<= 1) {
        float tc = __shfl_up(pc, o, 64);
        float tp = __shfl_up(pp, o, 64);
        if (lane >= o) { pc += tc; pp += tp; }
    }
    float totc = __shfl(pc, 63, 64);
    float totp = __shfl(pp, 63, 64);
    float sufc = totc - pc;
    float sufp = totp - pp;

    float n_pos  = bstats[b * 4 + 0];
    float n_negt = bstats[b * 4 + 1];
    float sp     = bstats[b * 4 + 2];
    float sp2    = bstats[b * 4 + 3];
    float n_sel  = fminf(3.0f * n_pos, n_negt);

    float hard_p2 = 0.f;
    bool cross = (sufc < n_sel) && (sufc + cg >= n_sel);
    unsigned long long bal = __ballot(cross);
    if (n_sel <= 0.f) {
        hard_p2 = 0.f;
    } else if (bal == 0ULL) {
        hard_p2 = totp;
    } else {
        int ls = 63 - __builtin_clzll(bal);
        float run  = __shfl(sufc, ls, 64);
        float runp = __shfl(sufp, ls, 64);
        float bc = 0.f, bp = 0.f;
        if (lane < SEG) {
            int idx = b * NBINS + ls * SEG + lane;
            bc = hist_cnt[idx];
            bp = hist_p2[idx];
        }
        float pc2 = bc, pp2 = bp;
        #pragma unroll
        for (int o = 1; o < 64; o <<= 1) {
            float tc = __shfl_up(pc2, o, 64);
            float tp = __shfl_up(pp2, o, 64);
            if (lane >= o) { pc2 += tc; pp2 += tp; }
        }
        float tot2c = __shfl(pc2, SEG - 1, 64);
        float tot2p = __shfl(pp2, SEG - 1, 64);
        float suf2c = tot2c - pc2;
        float suf2p = tot2p - pp2;
        bool cross2 = (lane < SEG) && (run + suf2c < n_sel) && (run + suf2c + bc >= n_sel);
        unsigned long long bal2 = __ballot(cross2);
        if (bal2 == 0ULL) {
            hard_p2 = runp + tot2p;
        } else {
            int ks = 63 - __builtin_clzll(bal2);
            float rs  = __shfl(suf2c, ks, 64);
            float rsp = __shfl(suf2p, ks, 64);
            float cc  = __shfl(bc, ks, 64);
            float cp  = __shfl(bp, ks, 64);
            float need = n_sel - (run + rs);
            hard_p2 = runp + rsp + (cc > 0.f ? cp * (need / cc) : 0.f);
        }
    }

    if (lane == 0) {
        float uni = sp2 + n_pos + hard_p2 + EPSF;
        btext[b] = 1.0f - 2.0f * sp / uni;
    }
    if (lane < NKER) {
        int idx = b * NKER + lane;
        float a = kstats[idx * 3 + 0];
        float u = kstats[idx * 3 + 1];
        float t = kstats[idx * 3 + 2];
        bkterm[idx] = 1.0f - 2.0f * a / (u + t + EPSF);
    }
}

__global__ __launch_bounds__(64) void combine_kernel(
    const float* __restrict__ btext, const float* __restrict__ bkterm,
    float* __restrict__ out)
{
    const int lane = threadIdx.x;
    float t = (lane < BB) ? btext[lane] : 0.f;
    float k = bkterm[lane];
    if (lane < BB * NKER - 64) k += bkterm[64 + lane];
    #define WRED(v) { for (int o_ = 32; o_ > 0; o_ >>= 1) v += __shfl_down(v, o_, 64); }
    WRED(t) WRED(k)
    #undef WRED
    if (lane == 0) {
        float lt = t / (float)BB;
        float lk = k / (float)(BB * NKER);
        out[0] = lk + 0.5f * lt;
        out[1] = lt;
        out[2] = lk;
    }
}

extern "C" void kernel_launch(void* const* d_in, const int* in_sizes, int n_in,
                              void* d_out, int out_size, void* d_ws, size_t ws_size,
                              hipStream_t stream)
{
    const float* pred    = (const float*)d_in[0];
    const float* gt_text = (const float*)d_in[1];
    const float* gt_k    = (const float*)d_in[2];
    const float* tmask   = (const float*)d_in[3];

    float* ws = (float*)d_ws;
    float* hist_cnt = ws;
    float* hist_p2  = ws + (size_t)BB * NBINS;
    float* bstats   = ws + (size_t)2 * BB * NBINS;          // BB*4
    float* kstats   = bstats + BB * 4;                      // BB*NKER*3
    float* btext    = kstats + BB * NKER * 3;               // BB
    float* bkterm   = btext + BB;                           // BB*NKER

    size_t zero_bytes = ((size_t)2 * BB * NBINS + BB * 4 + BB * NKER * 3) * sizeof(float);
    hipMemsetAsync(d_ws, 0, zero_bytes, stream);

    dim3 grid(CHUNKS, BB), block(256);
    hipLaunchKernelGGL(pass1_kernel, grid, block, 0, stream,
                       pred, gt_text, gt_k, tmask, hist_cnt, hist_p2, bstats, kstats);
    hipLaunchKernelGGL(finalize_batch_kernel, dim3(BB), dim3(64), 0, stream,
                       hist_cnt, hist_p2, bstats, kstats, btext, bkterm);
    hipLaunchKernelGGL(combine_kernel, dim3(1), dim3(64), 0, stream,
                       btext, bkterm, (float*)d_out);
}

// Round 5
// 361.635 us; speedup vs baseline: 1.1224x; 1.1224x over previous
//
#include <hip/hip_runtime.h>
#include <math.h>

#define HW 409600
#define BB 16
#define CPRED 6
#define NKER 5
#define NBINS 1024
#define EPSF 1e-6f

#define HW4 (HW / 4)          // 102400 float4 per channel per batch
#define TILE4 256             // float4 per channel per tile (1024 pixels)
#define NCH 13
#define CHELEM (NCH * TILE4)  // 3328 float4 per buffer
#define SEGS 16
#define TILES_PER_SEG 25      // 16*25*256 = 102400

__device__ __forceinline__ float sigmoidf_(float x) {
    return __builtin_amdgcn_rcpf(1.0f + __expf(-x));
}

__global__ __launch_bounds__(256) void pass1_kernel(
    const float* __restrict__ pred, const float* __restrict__ gt_text,
    const float* __restrict__ gt_k, const float* __restrict__ tmask,
    float* __restrict__ hist_cnt, float* __restrict__ hist_p2,
    float* __restrict__ bstats, float* __restrict__ kstats)
{
    __shared__ float4 sbuf[2 * CHELEM];     // 104 KB double-buffered tile
    __shared__ float s_cnt[NBINS];          // 4 KB
    __shared__ float s_p2[NBINS];           // 4 KB
    __shared__ float s_red[19][4];

    const int seg = blockIdx.x;
    const int b = blockIdx.y;
    const int tid = threadIdx.x;
    const int lane = tid & 63;
    const int wv = tid >> 6;

    for (int i = tid; i < NBINS; i += 256) { s_cnt[i] = 0.f; s_p2[i] = 0.f; }
    __syncthreads();

    const float4* P  = reinterpret_cast<const float4*>(pred)    + (size_t)b * CPRED * HW4;
    const float4* GT = reinterpret_cast<const float4*>(gt_text) + (size_t)b * HW4;
    const float4* GK = reinterpret_cast<const float4*>(gt_k)    + (size_t)b * NKER * HW4;
    const float4* TM = reinterpret_cast<const float4*>(tmask)   + (size_t)b * HW4;

    // Each wave stages quarter q=wv of every channel and later computes
    // exactly those pixels (tid's quarter == its own wave) -> no barriers.
    #define STG(c, bp) { \
        const float4* ga_ = (bp) + (size_t)t_ * TILE4 + wv * 64 + lane; \
        __builtin_amdgcn_global_load_lds( \
            (const __attribute__((address_space(1))) void*)ga_, \
            (__attribute__((address_space(3))) void*)&sbuf[nb_ * CHELEM + (c) * TILE4 + wv * 64], \
            16, 0, 0); \
    }
    #define STAGE_ALL(nbv, tv) { \
        const int nb_ = (nbv); const int t_ = (tv); \
        STG(0, P) STG(1, P + HW4) STG(2, P + 2 * HW4) \
        STG(3, P + 3 * HW4) STG(4, P + 4 * HW4) STG(5, P + 5 * HW4) \
        STG(6, GT) \
        STG(7, GK) STG(8, GK + HW4) STG(9, GK + 2 * HW4) \
        STG(10, GK + 3 * HW4) STG(11, GK + 4 * HW4) \
        STG(12, TM) \
    }

    float n_pos = 0.f, n_neg = 0.f, sp = 0.f, sp2 = 0.f;
    float kin0 = 0.f, kin1 = 0.f, kin2 = 0.f, kin3 = 0.f, kin4 = 0.f;
    float kui0 = 0.f, kui1 = 0.f, kui2 = 0.f, kui3 = 0.f, kui4 = 0.f;
    float kut0 = 0.f, kut1 = 0.f, kut2 = 0.f, kut3 = 0.f, kut4 = 0.f;

    #define TEXT1(mm, xx, ggt) { \
        float p = sigmoidf_(xx); \
        float posf = (mm) * (ggt); \
        float negf = (mm) - posf; \
        n_pos += posf; n_neg += negf; \
        sp += posf * p; sp2 += posf * p * p; \
        if (negf > 0.f) { \
            int bin = (int)(p * (float)NBINS); \
            bin = bin > NBINS - 1 ? NBINS - 1 : bin; \
            atomicAdd(&s_cnt[bin], 1.f); \
            atomicAdd(&s_p2[bin], p * p); \
        } \
    }
    #define KCH(xk, gg, kin, kui, kut) { \
        float p0 = sigmoidf_(xk.x), p1 = sigmoidf_(xk.y); \
        float p2_ = sigmoidf_(xk.z), p3 = sigmoidf_(xk.w); \
        kin += m4.x * p0 * gg.x + m4.y * p1 * gg.y \
             + m4.z * p2_ * gg.z + m4.w * p3 * gg.w; \
        kui += m4.x * p0 * p0 + m4.y * p1 * p1 \
             + m4.z * p2_ * p2_ + m4.w * p3 * p3; \
        kut += m4.x * gg.x + m4.y * gg.y + m4.z * gg.z + m4.w * gg.w; \
    }

    const int t0 = seg * TILES_PER_SEG;
    STAGE_ALL(0, t0)                                   // prologue: 13 loads in flight

    for (int k = 0; k < TILES_PER_SEG; ++k) {
        const int cur = k & 1;
        if (k < TILES_PER_SEG - 1) {
            STAGE_ALL(cur ^ 1, t0 + k + 1)             // 26 in flight
            asm volatile("s_waitcnt vmcnt(13)" ::: "memory");   // cur's 13 done
        } else {
            asm volatile("s_waitcnt vmcnt(0)" ::: "memory");
        }
        __builtin_amdgcn_sched_barrier(0);

        const int o = cur * CHELEM + tid;
        float4 x4  = sbuf[o + 0 * TILE4];
        float4 xk0 = sbuf[o + 1 * TILE4];
        float4 xk1 = sbuf[o + 2 * TILE4];
        float4 xk2 = sbuf[o + 3 * TILE4];
        float4 xk3 = sbuf[o + 4 * TILE4];
        float4 xk4 = sbuf[o + 5 * TILE4];
        float4 g4  = sbuf[o + 6 * TILE4];
        float4 gg0 = sbuf[o + 7 * TILE4];
        float4 gg1 = sbuf[o + 8 * TILE4];
        float4 gg2 = sbuf[o + 9 * TILE4];
        float4 gg3 = sbuf[o + 10 * TILE4];
        float4 gg4 = sbuf[o + 11 * TILE4];
        float4 m4  = sbuf[o + 12 * TILE4];

        TEXT1(m4.x, x4.x, g4.x)
        TEXT1(m4.y, x4.y, g4.y)
        TEXT1(m4.z, x4.z, g4.z)
        TEXT1(m4.w, x4.w, g4.w)
        KCH(xk0, gg0, kin0, kui0, kut0)
        KCH(xk1, gg1, kin1, kui1, kut1)
        KCH(xk2, gg2, kin2, kui2, kut2)
        KCH(xk3, gg3, kin3, kui3, kut3)
        KCH(xk4, gg4, kin4, kui4, kut4)
        __builtin_amdgcn_sched_barrier(0);   // keep next stage's writes after these reads
    }
    #undef STG
    #undef STAGE_ALL
    #undef TEXT1
    #undef KCH

    // wave reduction -> LDS -> one global atomic per quantity per block
    float kin[NKER] = {kin0, kin1, kin2, kin3, kin4};
    float kui[NKER] = {kui0, kui1, kui2, kui3, kui4};
    float kut[NKER] = {kut0, kut1, kut2, kut3, kut4};
    #define WRED(v) { for (int o_ = 32; o_ > 0; o_ >>= 1) v += __shfl_down(v, o_, 64); }
    WRED(n_pos) WRED(n_neg) WRED(sp) WRED(sp2)
    if (lane == 0) {
        s_red[0][wv] = n_pos; s_red[1][wv] = n_neg;
        s_red[2][wv] = sp;    s_red[3][wv] = sp2;
    }
    #pragma unroll
    for (int c = 0; c < NKER; ++c) {
        float a = kin[c], u = kui[c], t = kut[c];
        WRED(a) WRED(u) WRED(t)
        if (lane == 0) {
            s_red[4 + c * 3 + 0][wv] = a;
            s_red[4 + c * 3 + 1][wv] = u;
            s_red[4 + c * 3 + 2][wv] = t;
        }
    }
    #undef WRED
    __syncthreads();

    if (tid < 19) {
        float a = s_red[tid][0] + s_red[tid][1] + s_red[tid][2] + s_red[tid][3];
        float* dst;
        if (tid < 4) dst = &bstats[b * 4 + tid];
        else {
            int q = tid - 4;
            dst = &kstats[(b * NKER + q / 3) * 3 + (q % 3)];
        }
        atomicAdd(dst, a);
    }

    for (int i = tid; i < NBINS; i += 256) {
        float c = s_cnt[i];
        if (c != 0.f) {
            atomicAdd(&hist_cnt[b * NBINS + i], c);
            atomicAdd(&hist_p2[b * NBINS + i], s_p2[i]);
        }
    }
}

// one block (1 wave) per batch
__global__ __launch_bounds__(64) void finalize_batch_kernel(
    const float* __restrict__ hist_cnt, const float* __restrict__ hist_p2,
    const float* __restrict__ bstats, const float* __restrict__ kstats,
    float* __restrict__ btext, float* __restrict__ bkterm)
{
    const int b = blockIdx.x;
    const int lane = threadIdx.x;
    const int SEG = NBINS / 64;   // 16 bins per lane

    float cg = 0.f, pg = 0.f;
    {
        int base = b * NBINS + lane * SEG;
        #pragma unroll
        for (int k = 0; k < SEG; ++k) {
            cg += hist_cnt[base + k];
            pg += hist_p2[base + k];
        }
    }
    float pc = cg, pp = pg;
    #pragma unroll
    for (int o = 1; o < 64; o <<= 1) {
        float tc = __shfl_up(pc, o, 64);
        float tp = __shfl_up(pp, o, 64);
        if (lane >= o) { pc += tc; pp += tp; }
    }
    float totc = __shfl(pc, 63, 64);
    float totp = __shfl(pp, 63, 64);
    float sufc = totc - pc;
    float sufp = totp - pp;

    float n_pos  = bstats[b * 4 + 0];
    float n_negt = bstats[b * 4 + 1];
    float sp     = bstats[b * 4 + 2];
    float sp2    = bstats[b * 4 + 3];
    float n_sel  = fminf(3.0f * n_pos, n_negt);

    float hard_p2 = 0.f;
    bool cross = (sufc < n_sel) && (sufc + cg >= n_sel);
    unsigned long long bal = __ballot(cross);
    if (n_sel <= 0.f) {
        hard_p2 = 0.f;
    } else if (bal == 0ULL) {
        hard_p2 = totp;
    } else {
        int ls = 63 - __builtin_clzll(bal);
        float run  = __shfl(sufc, ls, 64);
        float runp = __shfl(sufp, ls, 64);
        float bc = 0.f, bp = 0.f;
        if (lane < SEG) {
            int idx = b * NBINS + ls * SEG + lane;
            bc = hist_cnt[idx];
            bp = hist_p2[idx];
        }
        float pc2 = bc, pp2 = bp;
        #pragma unroll
        for (int o = 1; o < 64; o <<= 1) {
            float tc = __shfl_up(pc2, o, 64);
            float tp = __shfl_up(pp2, o, 64);
            if (lane >= o) { pc2 += tc; pp2 += tp; }
        }
        float tot2c = __shfl(pc2, SEG - 1, 64);
        float tot2p = __shfl(pp2, SEG - 1, 64);
        float suf2c = tot2c - pc2;
        float suf2p = tot2p - pp2;
        bool cross2 = (lane < SEG) && (run + suf2c < n_sel) && (run + suf2c + bc >= n_sel);
        unsigned long long bal2 = __ballot(cross2);
        if (bal2 == 0ULL) {
            hard_p2 = runp + tot2p;
        } else {
            int ks = 63 - __builtin_clzll(bal2);
            float rs  = __shfl(suf2c, ks, 64);
            float rsp = __shfl(suf2p, ks, 64);
            float cc  = __shfl(bc, ks, 64);
            float cp  = __shfl(bp, ks, 64);
            float need = n_sel - (run + rs);
            hard_p2 = runp + rsp + (cc > 0.f ? cp * (need / cc) : 0.f);
        }
    }

    if (lane == 0) {
        float uni = sp2 + n_pos + hard_p2 + EPSF;
        btext[b] = 1.0f - 2.0f * sp / uni;
    }
    if (lane < NKER) {
        int idx = b * NKER + lane;
        float a = kstats[idx * 3 + 0];
        float u = kstats[idx * 3 + 1];
        float t = kstats[idx * 3 + 2];
        bkterm[idx] = 1.0f - 2.0f * a / (u + t + EPSF);
    }
}

__global__ __launch_bounds__(64) void combine_kernel(
    const float* __restrict__ btext, const float* __restrict__ bkterm,
    float* __restrict__ out)
{
    const int lane = threadIdx.x;
    float t = (lane < BB) ? btext[lane] : 0.f;
    float k = bkterm[lane];
    if (lane < BB * NKER - 64) k += bkterm[64 + lane];
    #define WRED(v) { for (int o_ = 32; o_ > 0; o_ >>= 1) v += __shfl_down(v, o_, 64); }
    WRED(t) WRED(k)
    #undef WRED
    if (lane == 0) {
        float lt = t / (float)BB;
        float lk = k / (float)(BB * NKER);
        out[0] = lk + 0.5f * lt;
        out[1] = lt;
        out[2] = lk;
    }
}

extern "C" void kernel_launch(void* const* d_in, const int* in_sizes, int n_in,
                              void* d_out, int out_size, void* d_ws, size_t ws_size,
                              hipStream_t stream)
{
    const float* pred    = (const float*)d_in[0];
    const float* gt_text = (const float*)d_in[1];
    const float* gt_k    = (const float*)d_in[2];
    const float* tmask   = (const float*)d_in[3];

    float* ws = (float*)d_ws;
    float* hist_cnt = ws;
    float* hist_p2  = ws + (size_t)BB * NBINS;
    float* bstats   = ws + (size_t)2 * BB * NBINS;          // BB*4
    float* kstats   = bstats + BB * 4;                      // BB*NKER*3
    float* btext    = kstats + BB * NKER * 3;               // BB
    float* bkterm   = btext + BB;                           // BB*NKER

    size_t zero_bytes = ((size_t)2 * BB * NBINS + BB * 4 + BB * NKER * 3) * sizeof(float);
    hipMemsetAsync(d_ws, 0, zero_bytes, stream);

    dim3 grid(SEGS, BB), block(256);
    hipLaunchKernelGGL(pass1_kernel, grid, block, 0, stream,
                       pred, gt_text, gt_k, tmask, hist_cnt, hist_p2, bstats, kstats);
    hipLaunchKernelGGL(finalize_batch_kernel, dim3(BB), dim3(64), 0, stream,
                       hist_cnt, hist_p2, bstats, kstats, btext, bkterm);
    hipLaunchKernelGGL(combine_kernel, dim3(1), dim3(64), 0, stream,
                       btext, bkterm, (float*)d_out);
}